// Round 16
// baseline (123.903 us; speedup 1.0000x reference)
//
#include <hip/hip_runtime.h>

#define TN 80000
#define HD 128
#define NE 1280000
#define NB 8
#define NPG 10000
#define NG 8000

#define NBUCK 625           // buckets of 128 nodes (dst>>7)
#define BCAP  2304          // per-bucket record capacity (avg 2048)
#define CHUNK 2048
#define NCHUNK (NE / CHUNK)                 // 625

#define PXH_BLK 1250        // x->bf16 first half: 1250 blocks x 512 thr x 8
#define PX2_BLK 2500        // x->bf16 second half: 2500 blocks x 256 thr x 8
#define PW_BLK 8            // weights: 8 blocks x 256 thr x 8 elems x 2 mats

typedef __attribute__((ext_vector_type(8))) short short8;
typedef __attribute__((ext_vector_type(4))) float f32x4;

__device__ __forceinline__ unsigned short f2bf(float f){
  unsigned int u = __float_as_uint(f);
  u = u + 0x7FFFu + ((u >> 16) & 1u);
  return (unsigned short)(u >> 16);
}

__device__ __forceinline__ short8 pack_bf8(float4 a, float4 b){
  short8 o;
  o[0] = (short)f2bf(a.x); o[1] = (short)f2bf(a.y); o[2] = (short)f2bf(a.z); o[3] = (short)f2bf(a.w);
  o[4] = (short)f2bf(b.x); o[5] = (short)f2bf(b.y); o[6] = (short)f2bf(b.z); o[7] = (short)f2bf(b.w);
  return o;
}

// blocks [0,NCHUNK): chunk-sort 2048 edges by bucket (dst>>7) ; NCHUNK: colsums ;
// rest: x->bf16 (first half) — overlaps cbin
// record: word0 = src | (dst&127)<<17 ; word1 = weight f32
__global__ __launch_bounds__(512) void k_prepbin(
    const float* __restrict__ Wrel2, const float* __restrict__ Wroot2, const float* __restrict__ brel2,
    float* __restrict__ crel, float* __restrict__ croot, float* __restrict__ cb,
    const int* __restrict__ src, const int* __restrict__ dst, const float* __restrict__ ew,
    int* __restrict__ gcur, int2* __restrict__ rec,
    const float* __restrict__ x, unsigned short* __restrict__ xb){
  int b = blockIdx.x;
  int t = threadIdx.x;
  if (b >= NCHUNK){
    if (b == NCHUNK){
      int k = t;
      if (k < HD){
        float a = 0.f, c = 0.f;
        for (int f = 0; f < HD; ++f){ a += Wrel2[f*HD + k]; c += Wroot2[f*HD + k]; }
        crel[k] = a; croot[k] = c;
        if (k == 0){ float s = 0.f; for (int f = 0; f < HD; ++f) s += brel2[f]; cb[0] = s; }
      }
      return;
    }
    size_t i = ((size_t)(b - NCHUNK - 1) * 512 + t) * 8;
    float4 a0 = *(const float4*)(x + i), a1 = *(const float4*)(x + i + 4);
    *(short8*)(xb + i) = pack_bf8(a0, a1);
    return;
  }
  // ---- cbin: 2048 edges, 4 per thread ----
  __shared__ int h[640];
  __shared__ int ex[640];
  __shared__ int2 grec[CHUNK];          // 16 KB
  __shared__ unsigned short gcb[CHUNK]; // 4 KB
  int base = b * CHUNK;

  for (int i = t; i < 640; i += 512) h[i] = 0;
  __syncthreads();

  int pa[4]; float pw[4]; int pc[4];
  #pragma unroll
  for (int k = 0; k < 4; ++k){
    int e = base + t + k * 512;
    int d = dst[e];
    int cbk = d >> 7;
    pa[k] = src[e] | ((d & 127) << 17);
    pw[k] = ew[e];
    pc[k] = cbk;
    atomicAdd(&h[cbk], 1);
  }
  __syncthreads();

  if (t < 64){
    int b0 = t * 10;
    int s = 0;
    #pragma unroll
    for (int j = 0; j < 10; ++j) s += h[b0 + j];
    int v = s;
    #pragma unroll
    for (int o = 1; o < 64; o <<= 1){ int q = __shfl_up(v, o); if (t >= o) v += q; }
    int run = v - s;
    #pragma unroll
    for (int j = 0; j < 10; ++j){ int q = h[b0 + j]; h[b0 + j] = run; ex[b0 + j] = run; run += q; }
  }
  __syncthreads();

  #pragma unroll
  for (int k = 0; k < 4; ++k){
    int p = atomicAdd(&h[pc[k]], 1);
    grec[p] = make_int2(pa[k], __float_as_int(pw[k]));
    gcb[p] = (unsigned short)pc[k];
  }
  __syncthreads();

  for (int i = t; i < NBUCK; i += 512){
    int cnt = h[i] - ex[i];
    int go = 0;
    if (cnt > 0) go = atomicAdd(&gcur[i], cnt);
    ex[i] = i * BCAP + go - ex[i];
  }
  __syncthreads();

  for (int p = t; p < CHUNK; p += 512){
    int cbk = gcb[p];
    int ga = ex[cbk] + p;
    if (ga < (cbk + 1) * BCAP) rec[ga] = grec[p];
  }
}

// blocks [0,NBUCK): per-bucket counting sort (256 thr) ; rest: x second half + W conv
__global__ __launch_bounds__(256) void k_nsconv(const int* __restrict__ gcur, int2* __restrict__ rec,
    int* __restrict__ startp, int* __restrict__ cntp,
    const float* __restrict__ x, unsigned short* __restrict__ xb,
    const float* __restrict__ W1, const float* __restrict__ W2,
    unsigned short* __restrict__ W1b, unsigned short* __restrict__ W2b){
  int b = blockIdx.x, t = threadIdx.x;
  if (b >= NBUCK){
    int cb2 = b - NBUCK;
    if (cb2 < PX2_BLK){
      size_t i = (size_t)TN * HD / 2 + ((size_t)cb2 * 256 + t) * 8;
      float4 a0 = *(const float4*)(x + i), a1 = *(const float4*)(x + i + 4);
      *(short8*)(xb + i) = pack_bf8(a0, a1);
    } else {
      size_t i = ((size_t)(cb2 - PX2_BLK) * 256 + t) * 8;
      float4 a0 = *(const float4*)(W1 + i), a1 = *(const float4*)(W1 + i + 4);
      *(short8*)(W1b + i) = pack_bf8(a0, a1);
      float4 c0 = *(const float4*)(W2 + i), c1 = *(const float4*)(W2 + i + 4);
      *(short8*)(W2b + i) = pack_bf8(c0, c1);
    }
    return;
  }
  // ---- nsort: counting sort of <=BCAP records by node (7-bit local id) ----
  __shared__ int cnt5[128], ex5[128], cur5[128];
  __shared__ int2 srec[BCAP];          // ~18.4 KB
  int n = gcur[b]; if (n > BCAP) n = BCAP;
  size_t e0 = (size_t)b * BCAP;
  if (t < 128) cnt5[t] = 0;
  __syncthreads();

  int2 rr[9];                           // BCAP/256 == 9
  #pragma unroll
  for (int k = 0; k < 9; ++k){
    int i = t + k * 256;
    if (i < n){
      rr[k] = rec[e0 + i];
      atomicAdd(&cnt5[(rr[k].x >> 17) & 127], 1);
    }
  }
  __syncthreads();

  if (t < 64){
    int b0 = t * 2;
    int s = cnt5[b0] + cnt5[b0 + 1];
    int v = s;
    #pragma unroll
    for (int o = 1; o < 64; o <<= 1){ int q = __shfl_up(v, o); if (t >= o) v += q; }
    int run = v - s;
    int q0 = cnt5[b0];
    ex5[b0] = run; cur5[b0] = run;
    ex5[b0 + 1] = run + q0; cur5[b0 + 1] = run + q0;
  }
  __syncthreads();

  #pragma unroll
  for (int k = 0; k < 9; ++k){
    int i = t + k * 256;
    if (i < n){
      int p = atomicAdd(&cur5[(rr[k].x >> 17) & 127], 1);
      srec[p] = rr[k];
    }
  }
  __syncthreads();

  #pragma unroll
  for (int k = 0; k < 9; ++k){
    int i = t + k * 256;
    if (i < n) rec[e0 + i] = srec[i];
  }
  if (t < 128){
    int node = b * 128 + t;
    if (node < TN){
      startp[node] = (int)e0 + ex5[t];
      cntp[node] = cnt5[t];
    }
  }
}

// ---- layer-1 aggregation: one wave per node, 16 edges in flight ----
__global__ __launch_bounds__(256) void k_gather(const int* __restrict__ startp, const int* __restrict__ cntp,
                                                const int2* __restrict__ rec,
                                                const unsigned short* __restrict__ xb, unsigned short* __restrict__ zb){
  int wid = threadIdx.x >> 6, lane = threadIdx.x & 63;
  int node = blockIdx.x * 4 + wid;
  int e0 = startp[node], e1 = e0 + cntp[node];
  int g  = lane >> 4;
  int sl = lane & 15;
  const uint4* xp = (const uint4*)xb;

  float acc[8] = {0,0,0,0,0,0,0,0};

  #define FMA8(P, W)                                                          \
    acc[0] += (W) * __uint_as_float((P).x << 16);                             \
    acc[1] += (W) * __uint_as_float((P).x & 0xFFFF0000u);                     \
    acc[2] += (W) * __uint_as_float((P).y << 16);                             \
    acc[3] += (W) * __uint_as_float((P).y & 0xFFFF0000u);                     \
    acc[4] += (W) * __uint_as_float((P).z << 16);                             \
    acc[5] += (W) * __uint_as_float((P).z & 0xFFFF0000u);                     \
    acc[6] += (W) * __uint_as_float((P).w << 16);                             \
    acc[7] += (W) * __uint_as_float((P).w & 0xFFFF0000u);

  int e = e0;
  for (; e + 16 <= e1; e += 16){
    int2 r0 = rec[e + g];
    int2 r1 = rec[e + 4 + g];
    int2 r2 = rec[e + 8 + g];
    int2 r3 = rec[e + 12 + g];
    uint4 p0 = xp[(size_t)(r0.x & 0x1FFFF) * 16 + sl];
    uint4 p1 = xp[(size_t)(r1.x & 0x1FFFF) * 16 + sl];
    uint4 p2 = xp[(size_t)(r2.x & 0x1FFFF) * 16 + sl];
    uint4 p3 = xp[(size_t)(r3.x & 0x1FFFF) * 16 + sl];
    float w0 = __int_as_float(r0.y);
    float w1 = __int_as_float(r1.y);
    float w2 = __int_as_float(r2.y);
    float w3 = __int_as_float(r3.y);
    FMA8(p0, w0)
    FMA8(p1, w1)
    FMA8(p2, w2)
    FMA8(p3, w3)
  }
  for (; e + 8 <= e1; e += 8){
    int2 r0 = rec[e + g];
    int2 r1 = rec[e + 4 + g];
    uint4 p0 = xp[(size_t)(r0.x & 0x1FFFF) * 16 + sl];
    uint4 p1 = xp[(size_t)(r1.x & 0x1FFFF) * 16 + sl];
    float w0 = __int_as_float(r0.y);
    float w1 = __int_as_float(r1.y);
    FMA8(p0, w0)
    FMA8(p1, w1)
  }
  if (e < e1){
    int ee = e + g;
    bool v0 = ee < e1;
    int2 r0 = rec[v0 ? ee : e0];
    int ee1 = e + 4 + g;
    bool v1 = ee1 < e1;
    int2 r1 = rec[v1 ? ee1 : e0];
    uint4 p0 = xp[(size_t)(r0.x & 0x1FFFF) * 16 + sl];
    uint4 p1 = xp[(size_t)(r1.x & 0x1FFFF) * 16 + sl];
    float w0 = v0 ? __int_as_float(r0.y) : 0.f;
    float w1 = v1 ? __int_as_float(r1.y) : 0.f;
    FMA8(p0, w0)
    FMA8(p1, w1)
  }
  #undef FMA8

  #pragma unroll
  for (int o = 16; o <= 32; o <<= 1){
    #pragma unroll
    for (int i = 0; i < 8; ++i) acc[i] += __shfl_xor(acc[i], o);
  }
  if (g == 0){
    uint4 o4;
    o4.x = ((unsigned)f2bf(acc[1]) << 16) | (unsigned)f2bf(acc[0]);
    o4.y = ((unsigned)f2bf(acc[3]) << 16) | (unsigned)f2bf(acc[2]);
    o4.z = ((unsigned)f2bf(acc[5]) << 16) | (unsigned)f2bf(acc[4]);
    o4.w = ((unsigned)f2bf(acc[7]) << 16) | (unsigned)f2bf(acc[6]);
    ((uint4*)zb)[(size_t)node * 16 + sl] = o4;
  }
}

// Fused: h = relu(z@W1^T + x@W2^T + b); u = h.crel; v = h.croot
// weights staged in LDS once per block (slot-major, conflict-free)
__global__ __launch_bounds__(256) void k_node(const unsigned short* __restrict__ zb, const unsigned short* __restrict__ xb,
    const unsigned short* __restrict__ W1b, const unsigned short* __restrict__ W2b,
    const float* __restrict__ brel1, const float* __restrict__ crel, const float* __restrict__ croot,
    float* __restrict__ u, float* __restrict__ v){
  __shared__ unsigned short Wl[2][16 * 128 * 8];   // 2 x 32 KB
  int tid = threadIdx.x;
  int wid = tid >> 6;
  int lane = tid & 63;
  int l15 = lane & 15;
  int g4 = lane >> 4;
  int nb = blockIdx.x * 128 + wid * 32;

  #pragma unroll
  for (int it = 0; it < 8; ++it){
    int slot = it * 2 + (tid >> 7);
    int kcol = tid & 127;
    int d0 = ((slot >> 2) << 5) + ((slot & 3) << 3);
    *(uint4*)&Wl[0][(slot * 128 + kcol) * 8] = *(const uint4*)&W1b[kcol * 128 + d0];
    *(uint4*)&Wl[1][(slot * 128 + kcol) * 8] = *(const uint4*)&W2b[kcol * 128 + d0];
  }

  short8 az[2][4], ax[2][4];
  #pragma unroll
  for (int nt = 0; nt < 2; ++nt){
    const unsigned short* zrow = zb + (size_t)(nb + nt * 16 + l15) * HD + g4 * 8;
    const unsigned short* xrow = xb + (size_t)(nb + nt * 16 + l15) * HD + g4 * 8;
    #pragma unroll
    for (int kk = 0; kk < 4; ++kk){
      az[nt][kk] = *(const short8*)(zrow + kk * 32);
      ax[nt][kk] = *(const short8*)(xrow + kk * 32);
    }
  }
  __syncthreads();

  float usum[2][4] = {{0,0,0,0},{0,0,0,0}}, vsum[2][4] = {{0,0,0,0},{0,0,0,0}};
  #pragma unroll
  for (int t = 0; t < 8; ++t){
    int kcol = t * 16 + l15;
    short8 w1f[4], w2f[4];
    #pragma unroll
    for (int kk = 0; kk < 4; ++kk){
      int slot = (kk << 2) | g4;
      w1f[kk] = *(const short8*)&Wl[0][(slot * 128 + kcol) * 8];
      w2f[kk] = *(const short8*)&Wl[1][(slot * 128 + kcol) * 8];
    }
    float bias = brel1[kcol], cr = crel[kcol], co = croot[kcol];
    #pragma unroll
    for (int nt = 0; nt < 2; ++nt){
      f32x4 acc = {0.f, 0.f, 0.f, 0.f};
      #pragma unroll
      for (int kk = 0; kk < 4; ++kk)
        acc = __builtin_amdgcn_mfma_f32_16x16x32_bf16(az[nt][kk], w1f[kk], acc, 0, 0, 0);
      #pragma unroll
      for (int kk = 0; kk < 4; ++kk)
        acc = __builtin_amdgcn_mfma_f32_16x16x32_bf16(ax[nt][kk], w2f[kk], acc, 0, 0, 0);
      #pragma unroll
      for (int r = 0; r < 4; ++r){
        float h = fmaxf(acc[r] + bias, 0.f);
        usum[nt][r] += h * cr;
        vsum[nt][r] += h * co;
      }
    }
  }
  #pragma unroll
  for (int o = 1; o < 16; o <<= 1){
    #pragma unroll
    for (int nt = 0; nt < 2; ++nt){
      #pragma unroll
      for (int r = 0; r < 4; ++r){
        usum[nt][r] += __shfl_xor(usum[nt][r], o);
        vsum[nt][r] += __shfl_xor(vsum[nt][r], o);
      }
    }
  }
  if (l15 == 0){
    #pragma unroll
    for (int nt = 0; nt < 2; ++nt){
      #pragma unroll
      for (int r = 0; r < 4; ++r){
        int node = nb + nt * 16 + g4 * 4 + r;
        u[node] = usum[nt][r];
        v[node] = vsum[nt][r];
      }
    }
  }
}

// ---- layer-2 collapsed aggregation: 16 lanes per node (coalesced rec reads) ----
__global__ __launch_bounds__(256) void k_pool2(const int* __restrict__ startp, const int* __restrict__ cntp,
                                               const int2* __restrict__ rec,
                                               const float* __restrict__ u, float* __restrict__ sacc){
  int t = threadIdx.x;
  int sg = t >> 4;
  int li = t & 15;
  int node = blockIdx.x * 16 + sg;
  if (node >= TN) return;
  if (node % NPG >= NG) return;
  int e0 = startp[node], cnt = cntp[node];
  float s = 0.f;
  for (int i = li; i < cnt; i += 16){
    int2 r = rec[e0 + i];
    s += __int_as_float(r.y) * u[r.x & 0x1FFFF];
  }
  #pragma unroll
  for (int o = 1; o < 16; o <<= 1) s += __shfl_xor(s, o);
  if (li == 0) sacc[node] = s;
}

__device__ __forceinline__ float blk_red_add16(float x, float* red){
  #pragma unroll
  for (int o = 32; o > 0; o >>= 1) x += __shfl_xor(x, o);
  int wid = threadIdx.x >> 6, lane = threadIdx.x & 63;
  __syncthreads();
  if (lane == 0) red[wid] = x;
  __syncthreads();
  float s = 0.f;
  #pragma unroll
  for (int j = 0; j < 16; ++j) s += red[j];
  return s;
}
__device__ __forceinline__ float blk_red_max16(float x, float* red){
  #pragma unroll
  for (int o = 32; o > 0; o >>= 1) x = fmaxf(x, __shfl_xor(x, o));
  int wid = threadIdx.x >> 6, lane = threadIdx.x & 63;
  __syncthreads();
  if (lane == 0) red[wid] = x;
  __syncthreads();
  float s = red[0];
  #pragma unroll
  for (int j = 1; j < 16; ++j) s = fmaxf(s, red[j]);
  return s;
}

__global__ __launch_bounds__(1024) void k_final(const float* __restrict__ s, const float* __restrict__ vv,
    const float* __restrict__ cbp, const float* __restrict__ gamma, const float* __restrict__ beta,
    float* __restrict__ out){
  __shared__ float t[NG];
  __shared__ float red[16];
  int b = blockIdx.x, tid = threadIdx.x;
  float cb = cbp[0];
  const float inv = 1.f / (float)HD;
  float lsum = 0.f, lsq = 0.f;
  for (int j = tid; j < NG; j += 1024){
    float g = (s[b*NPG + j] + vv[b*NPG + j] + cb) * inv;
    t[j] = g; lsum += g; lsq += g * g;
  }
  float S1 = blk_red_add16(lsum, red);
  float S2 = blk_red_add16(lsq, red);
  float mu = S1 / (float)NG;
  float var = S2 / (float)NG - mu * mu;
  float rstd = rsqrtf(var + 1e-5f);
  float lmax = -3.4e38f;
  for (int j = tid; j < NG; j += 1024){
    float tj = (t[j] - mu) * rstd * gamma[j] + beta[j];
    t[j] = tj; lmax = fmaxf(lmax, tj);
  }
  float M = blk_red_max16(lmax, red);
  float lexp = 0.f;
  for (int j = tid; j < NG; j += 1024) lexp += expf(t[j] - M);
  float S = blk_red_add16(lexp, red);
  float lse = M + logf(S);
  for (int j = tid; j < NG; j += 1024) out[b*NG + j] = t[j] - lse;
}

extern "C" void kernel_launch(void* const* d_in, const int* in_sizes, int n_in,
                              void* d_out, int out_size, void* d_ws, size_t ws_size,
                              hipStream_t stream){
  const float* x      = (const float*)d_in[0];
  const int*   ei     = (const int*)d_in[1];
  const float* ew     = (const float*)d_in[3];
  const float* Wrel1  = (const float*)d_in[4];
  const float* brel1  = (const float*)d_in[5];
  const float* Wroot1 = (const float*)d_in[6];
  const float* Wrel2  = (const float*)d_in[7];
  const float* brel2  = (const float*)d_in[8];
  const float* Wroot2 = (const float*)d_in[9];
  const float* gamma  = (const float*)d_in[10];
  const float* beta   = (const float*)d_in[11];
  const int*   src    = ei;
  const int*   dst    = ei + NE;

  char* ws = (char*)d_ws;
  size_t off_b = 0;
  auto alloc = [&](size_t bytes) -> char* {
    char* p = ws + off_b;
    off_b += (bytes + 511) & ~(size_t)511;
    return p;
  };
  unsigned short* xb    = (unsigned short*)alloc((size_t)TN * HD * 2);
  unsigned short* zb    = (unsigned short*)alloc((size_t)TN * HD * 2);
  unsigned short* W1b   = (unsigned short*)alloc(HD * HD * 2);
  unsigned short* W2b   = (unsigned short*)alloc(HD * HD * 2);
  float*          crel  = (float*)alloc(HD * 4);
  float*          croot = (float*)alloc(HD * 4);
  float*          cbp   = (float*)alloc(4);
  float*          u     = (float*)alloc(TN * 4);
  float*          v     = (float*)alloc(TN * 4);
  float*          sacc  = (float*)alloc(TN * 4);
  int*            startp= (int*)alloc(TN * 4);
  int*            cntp  = (int*)alloc(TN * 4);
  int*            gcur  = (int*)alloc(NBUCK * 4);
  int2*           rec   = (int2*)alloc((size_t)NBUCK * BCAP * 8);

  hipMemsetAsync(gcur, 0, NBUCK * 4, stream);

  k_prepbin<<<NCHUNK + 1 + PXH_BLK, 512, 0, stream>>>(
      Wrel2, Wroot2, brel2, crel, croot, cbp,
      src, dst, ew, gcur, rec, x, xb);
  k_nsconv<<<NBUCK + PX2_BLK + PW_BLK, 256, 0, stream>>>(gcur, rec, startp, cntp,
                                                         x, xb, Wrel1, Wroot1, W1b, W2b);
  k_gather<<<TN/4, 256, 0, stream>>>(startp, cntp, rec, xb, zb);
  k_node  <<<TN/128, 256, 0, stream>>>(zb, xb, W1b, W2b, brel1, crel, croot, u, v);
  k_pool2 <<<(TN+15)/16, 256, 0, stream>>>(startp, cntp, rec, u, sacc);
  k_final <<<NB, 1024, 0, stream>>>(sacc, v, cbp, gamma, beta, (float*)d_out);
}

// Round 17
// 114.243 us; speedup vs baseline: 1.0846x; 1.0846x over previous
//
#include <hip/hip_runtime.h>

#define TN 80000
#define HD 128
#define NE 1280000
#define NB 8
#define NPG 10000
#define NG 8000

#define NBUCK 625           // buckets of 128 nodes (dst>>7)
#define BCAP  2304          // per-bucket record capacity (avg 2048)
#define CHUNK 4096
#define NCHUNK ((NE + CHUNK - 1) / CHUNK)   // 313

#define PX_BLK 2500         // x->bf16: 2500 blocks x 512 thr x 8 elems
#define PW_BLK 32           // weights->bf16: 16384 elems / 512

typedef __attribute__((ext_vector_type(8))) short short8;
typedef __attribute__((ext_vector_type(4))) float f32x4;

__device__ __forceinline__ unsigned short f2bf(float f){
  unsigned int u = __float_as_uint(f);
  u = u + 0x7FFFu + ((u >> 16) & 1u);
  return (unsigned short)(u >> 16);
}

__device__ __forceinline__ short8 pack_bf8(float4 a, float4 b){
  short8 o;
  o[0] = (short)f2bf(a.x); o[1] = (short)f2bf(a.y); o[2] = (short)f2bf(a.z); o[3] = (short)f2bf(a.w);
  o[4] = (short)f2bf(b.x); o[5] = (short)f2bf(b.y); o[6] = (short)f2bf(b.z); o[7] = (short)f2bf(b.w);
  return o;
}

// blocks [0,NCHUNK): chunk-sort edges by bucket (dst>>7) ; NCHUNK: colsums ;
// rest: x->bf16 and W->bf16 conversions (independent work, overlaps cbin)
// record: word0 = src | (dst&127)<<17 ; word1 = weight f32
__global__ __launch_bounds__(512) void k_prepbin(
    const float* __restrict__ Wrel2, const float* __restrict__ Wroot2, const float* __restrict__ brel2,
    float* __restrict__ crel, float* __restrict__ croot, float* __restrict__ cb,
    const int* __restrict__ src, const int* __restrict__ dst, const float* __restrict__ ew,
    int* __restrict__ gcur, int2* __restrict__ rec,
    const float* __restrict__ x, unsigned short* __restrict__ xb,
    const float* __restrict__ W1, const float* __restrict__ W2,
    unsigned short* __restrict__ W1b, unsigned short* __restrict__ W2b){
  int b = blockIdx.x;
  int t = threadIdx.x;
  if (b >= NCHUNK){
    if (b == NCHUNK){
      int k = t;
      if (k < HD){
        float a = 0.f, c = 0.f;
        for (int f = 0; f < HD; ++f){ a += Wrel2[f*HD + k]; c += Wroot2[f*HD + k]; }
        crel[k] = a; croot[k] = c;
        if (k == 0){ float s = 0.f; for (int f = 0; f < HD; ++f) s += brel2[f]; cb[0] = s; }
      }
      return;
    }
    int cb2 = b - NCHUNK - 1;
    if (cb2 < PX_BLK){
      size_t i = ((size_t)cb2 * 512 + t) * 8;
      float4 a0 = *(const float4*)(x + i), a1 = *(const float4*)(x + i + 4);
      *(short8*)(xb + i) = pack_bf8(a0, a1);
    } else {
      int i = (cb2 - PX_BLK) * 512 + t;
      W1b[i] = f2bf(W1[i]);
      W2b[i] = f2bf(W2[i]);
    }
    return;
  }
  // ---- cbin ----
  __shared__ int h[640];
  __shared__ int ex[640];
  __shared__ int2 grec[CHUNK];          // 32 KB
  __shared__ unsigned short gcb[CHUNK]; // 8 KB
  int base = b * CHUNK;
  int n = NE - base; if (n > CHUNK) n = CHUNK;

  for (int i = t; i < 640; i += 512) h[i] = 0;
  __syncthreads();

  int pa[8]; float pw[8]; int pc[8];
  #pragma unroll
  for (int k = 0; k < 8; ++k){
    int idx = t + k * 512;
    if (idx < n){
      int e = base + idx;
      int d = dst[e];
      int cbk = d >> 7;
      pa[k] = src[e] | ((d & 127) << 17);
      pw[k] = ew[e];
      pc[k] = cbk;
      atomicAdd(&h[cbk], 1);
    } else pc[k] = -1;
  }
  __syncthreads();

  if (t < 64){
    int b0 = t * 10;
    int s = 0;
    #pragma unroll
    for (int j = 0; j < 10; ++j) s += h[b0 + j];
    int v = s;
    #pragma unroll
    for (int o = 1; o < 64; o <<= 1){ int q = __shfl_up(v, o); if (t >= o) v += q; }
    int run = v - s;
    #pragma unroll
    for (int j = 0; j < 10; ++j){ int q = h[b0 + j]; h[b0 + j] = run; ex[b0 + j] = run; run += q; }
  }
  __syncthreads();

  #pragma unroll
  for (int k = 0; k < 8; ++k){
    if (pc[k] >= 0){
      int p = atomicAdd(&h[pc[k]], 1);
      grec[p] = make_int2(pa[k], __float_as_int(pw[k]));
      gcb[p] = (unsigned short)pc[k];
    }
  }
  __syncthreads();

  for (int i = t; i < NBUCK; i += 512){
    int cnt = h[i] - ex[i];
    int go = 0;
    if (cnt > 0) go = atomicAdd(&gcur[i], cnt);
    ex[i] = i * BCAP + go - ex[i];
  }
  __syncthreads();

  for (int p = t; p < n; p += 512){
    int cbk = gcb[p];
    int ga = ex[cbk] + p;
    if (ga < (cbk + 1) * BCAP) rec[ga] = grec[p];
  }
}

// pure nsort: per-bucket counting sort by node (7-bit local id) -> start/cnt
__global__ __launch_bounds__(512) void k_nsort(const int* __restrict__ gcur, int2* __restrict__ rec,
                                               int* __restrict__ startp, int* __restrict__ cntp){
  __shared__ int cnt5[128], ex5[128], cur5[128];
  __shared__ int2 srec[BCAP];          // ~18.4 KB
  int t = threadIdx.x, b = blockIdx.x;
  int n = gcur[b]; if (n > BCAP) n = BCAP;
  size_t e0 = (size_t)b * BCAP;
  if (t < 128) cnt5[t] = 0;
  __syncthreads();

  int2 rr[5];
  #pragma unroll
  for (int k = 0; k < 5; ++k){
    int i = t + k * 512;
    if (i < n){
      rr[k] = rec[e0 + i];
      atomicAdd(&cnt5[(rr[k].x >> 17) & 127], 1);
    }
  }
  __syncthreads();

  if (t < 64){
    int b0 = t * 2;
    int s = cnt5[b0] + cnt5[b0 + 1];
    int v = s;
    #pragma unroll
    for (int o = 1; o < 64; o <<= 1){ int q = __shfl_up(v, o); if (t >= o) v += q; }
    int run = v - s;
    int q0 = cnt5[b0];
    ex5[b0] = run; cur5[b0] = run;
    ex5[b0 + 1] = run + q0; cur5[b0 + 1] = run + q0;
  }
  __syncthreads();

  #pragma unroll
  for (int k = 0; k < 5; ++k){
    int i = t + k * 512;
    if (i < n){
      int p = atomicAdd(&cur5[(rr[k].x >> 17) & 127], 1);
      srec[p] = rr[k];
    }
  }
  __syncthreads();

  #pragma unroll
  for (int k = 0; k < 5; ++k){
    int i = t + k * 512;
    if (i < n) rec[e0 + i] = srec[i];
  }
  if (t < 128){
    int node = b * 128 + t;
    if (node < TN){
      startp[node] = (int)e0 + ex5[t];
      cntp[node] = cnt5[t];
    }
  }
}

// ---- layer-1 aggregation: one wave per node, 16 edges in flight ----
__global__ __launch_bounds__(256) void k_gather(const int* __restrict__ startp, const int* __restrict__ cntp,
                                                const int2* __restrict__ rec,
                                                const unsigned short* __restrict__ xb, unsigned short* __restrict__ zb){
  int wid = threadIdx.x >> 6, lane = threadIdx.x & 63;
  int node = blockIdx.x * 4 + wid;
  int e0 = startp[node], e1 = e0 + cntp[node];
  int g  = lane >> 4;
  int sl = lane & 15;
  const uint4* xp = (const uint4*)xb;

  float acc[8] = {0,0,0,0,0,0,0,0};

  #define FMA8(P, W)                                                          \
    acc[0] += (W) * __uint_as_float((P).x << 16);                             \
    acc[1] += (W) * __uint_as_float((P).x & 0xFFFF0000u);                     \
    acc[2] += (W) * __uint_as_float((P).y << 16);                             \
    acc[3] += (W) * __uint_as_float((P).y & 0xFFFF0000u);                     \
    acc[4] += (W) * __uint_as_float((P).z << 16);                             \
    acc[5] += (W) * __uint_as_float((P).z & 0xFFFF0000u);                     \
    acc[6] += (W) * __uint_as_float((P).w << 16);                             \
    acc[7] += (W) * __uint_as_float((P).w & 0xFFFF0000u);

  int e = e0;
  for (; e + 16 <= e1; e += 16){
    int2 r0 = rec[e + g];
    int2 r1 = rec[e + 4 + g];
    int2 r2 = rec[e + 8 + g];
    int2 r3 = rec[e + 12 + g];
    uint4 p0 = xp[(size_t)(r0.x & 0x1FFFF) * 16 + sl];
    uint4 p1 = xp[(size_t)(r1.x & 0x1FFFF) * 16 + sl];
    uint4 p2 = xp[(size_t)(r2.x & 0x1FFFF) * 16 + sl];
    uint4 p3 = xp[(size_t)(r3.x & 0x1FFFF) * 16 + sl];
    float w0 = __int_as_float(r0.y);
    float w1 = __int_as_float(r1.y);
    float w2 = __int_as_float(r2.y);
    float w3 = __int_as_float(r3.y);
    FMA8(p0, w0)
    FMA8(p1, w1)
    FMA8(p2, w2)
    FMA8(p3, w3)
  }
  for (; e + 8 <= e1; e += 8){
    int2 r0 = rec[e + g];
    int2 r1 = rec[e + 4 + g];
    uint4 p0 = xp[(size_t)(r0.x & 0x1FFFF) * 16 + sl];
    uint4 p1 = xp[(size_t)(r1.x & 0x1FFFF) * 16 + sl];
    float w0 = __int_as_float(r0.y);
    float w1 = __int_as_float(r1.y);
    FMA8(p0, w0)
    FMA8(p1, w1)
  }
  if (e < e1){
    int ee = e + g;
    bool v0 = ee < e1;
    int2 r0 = rec[v0 ? ee : e0];
    int ee1 = e + 4 + g;
    bool v1 = ee1 < e1;
    int2 r1 = rec[v1 ? ee1 : e0];
    uint4 p0 = xp[(size_t)(r0.x & 0x1FFFF) * 16 + sl];
    uint4 p1 = xp[(size_t)(r1.x & 0x1FFFF) * 16 + sl];
    float w0 = v0 ? __int_as_float(r0.y) : 0.f;
    float w1 = v1 ? __int_as_float(r1.y) : 0.f;
    FMA8(p0, w0)
    FMA8(p1, w1)
  }
  #undef FMA8

  #pragma unroll
  for (int o = 16; o <= 32; o <<= 1){
    #pragma unroll
    for (int i = 0; i < 8; ++i) acc[i] += __shfl_xor(acc[i], o);
  }
  if (g == 0){
    uint4 o4;
    o4.x = ((unsigned)f2bf(acc[1]) << 16) | (unsigned)f2bf(acc[0]);
    o4.y = ((unsigned)f2bf(acc[3]) << 16) | (unsigned)f2bf(acc[2]);
    o4.z = ((unsigned)f2bf(acc[5]) << 16) | (unsigned)f2bf(acc[4]);
    o4.w = ((unsigned)f2bf(acc[7]) << 16) | (unsigned)f2bf(acc[6]);
    ((uint4*)zb)[(size_t)node * 16 + sl] = o4;
  }
}

// Fused: h = relu(z@W1^T + x@W2^T + b); u = h.crel; v = h.croot
// weights staged in LDS once per block (slot-major layout: conflict-free
// stores and conflict-free ds_read_b128 in the MFMA loop)
__global__ __launch_bounds__(256) void k_node(const unsigned short* __restrict__ zb, const unsigned short* __restrict__ xb,
    const unsigned short* __restrict__ W1b, const unsigned short* __restrict__ W2b,
    const float* __restrict__ brel1, const float* __restrict__ crel, const float* __restrict__ croot,
    float* __restrict__ u, float* __restrict__ v){
  __shared__ unsigned short Wl[2][16 * 128 * 8];   // 2 x 32 KB, [mat][(slot*128+kcol)*8+j]
  int tid = threadIdx.x;
  int wid = tid >> 6;
  int lane = tid & 63;
  int l15 = lane & 15;
  int g4 = lane >> 4;
  int nb = blockIdx.x * 128 + wid * 32;

  // stage weights: slot = (kk*4+g4), d0 = kk*32+g4*8 = (slot>>2)*32+(slot&3)*8
  #pragma unroll
  for (int it = 0; it < 8; ++it){
    int slot = it * 2 + (tid >> 7);
    int kcol = tid & 127;
    int d0 = ((slot >> 2) << 5) + ((slot & 3) << 3);
    *(uint4*)&Wl[0][(slot * 128 + kcol) * 8] = *(const uint4*)&W1b[kcol * 128 + d0];
    *(uint4*)&Wl[1][(slot * 128 + kcol) * 8] = *(const uint4*)&W2b[kcol * 128 + d0];
  }

  short8 az[2][4], ax[2][4];
  #pragma unroll
  for (int nt = 0; nt < 2; ++nt){
    const unsigned short* zrow = zb + (size_t)(nb + nt * 16 + l15) * HD + g4 * 8;
    const unsigned short* xrow = xb + (size_t)(nb + nt * 16 + l15) * HD + g4 * 8;
    #pragma unroll
    for (int kk = 0; kk < 4; ++kk){
      az[nt][kk] = *(const short8*)(zrow + kk * 32);
      ax[nt][kk] = *(const short8*)(xrow + kk * 32);
    }
  }
  __syncthreads();

  float usum[2][4] = {{0,0,0,0},{0,0,0,0}}, vsum[2][4] = {{0,0,0,0},{0,0,0,0}};
  #pragma unroll
  for (int t = 0; t < 8; ++t){
    int kcol = t * 16 + l15;
    short8 w1f[4], w2f[4];
    #pragma unroll
    for (int kk = 0; kk < 4; ++kk){
      int slot = (kk << 2) | g4;
      w1f[kk] = *(const short8*)&Wl[0][(slot * 128 + kcol) * 8];
      w2f[kk] = *(const short8*)&Wl[1][(slot * 128 + kcol) * 8];
    }
    float bias = brel1[kcol], cr = crel[kcol], co = croot[kcol];
    #pragma unroll
    for (int nt = 0; nt < 2; ++nt){
      f32x4 acc = {0.f, 0.f, 0.f, 0.f};
      #pragma unroll
      for (int kk = 0; kk < 4; ++kk)
        acc = __builtin_amdgcn_mfma_f32_16x16x32_bf16(az[nt][kk], w1f[kk], acc, 0, 0, 0);
      #pragma unroll
      for (int kk = 0; kk < 4; ++kk)
        acc = __builtin_amdgcn_mfma_f32_16x16x32_bf16(ax[nt][kk], w2f[kk], acc, 0, 0, 0);
      #pragma unroll
      for (int r = 0; r < 4; ++r){
        float h = fmaxf(acc[r] + bias, 0.f);
        usum[nt][r] += h * cr;
        vsum[nt][r] += h * co;
      }
    }
  }
  #pragma unroll
  for (int o = 1; o < 16; o <<= 1){
    #pragma unroll
    for (int nt = 0; nt < 2; ++nt){
      #pragma unroll
      for (int r = 0; r < 4; ++r){
        usum[nt][r] += __shfl_xor(usum[nt][r], o);
        vsum[nt][r] += __shfl_xor(vsum[nt][r], o);
      }
    }
  }
  if (l15 == 0){
    #pragma unroll
    for (int nt = 0; nt < 2; ++nt){
      #pragma unroll
      for (int r = 0; r < 4; ++r){
        int node = nb + nt * 16 + g4 * 4 + r;
        u[node] = usum[nt][r];
        v[node] = vsum[nt][r];
      }
    }
  }
}

// ---- layer-2 collapsed aggregation: 16 lanes per node (coalesced rec reads) ----
__global__ __launch_bounds__(256) void k_pool2(const int* __restrict__ startp, const int* __restrict__ cntp,
                                               const int2* __restrict__ rec,
                                               const float* __restrict__ u, float* __restrict__ sacc){
  int t = threadIdx.x;
  int sg = t >> 4;          // 16 node-subgroups per block
  int li = t & 15;
  int node = blockIdx.x * 16 + sg;
  if (node >= TN) return;
  if (node % NPG >= NG) return;   // never read by k_final
  int e0 = startp[node], cnt = cntp[node];
  float s = 0.f;
  for (int i = li; i < cnt; i += 16){
    int2 r = rec[e0 + i];
    s += __int_as_float(r.y) * u[r.x & 0x1FFFF];
  }
  #pragma unroll
  for (int o = 1; o < 16; o <<= 1) s += __shfl_xor(s, o);
  if (li == 0) sacc[node] = s;
}

// generic block reduction for 1024 threads (16 waves)
__device__ __forceinline__ float blk_red_add16(float x, float* red){
  #pragma unroll
  for (int o = 32; o > 0; o >>= 1) x += __shfl_xor(x, o);
  int wid = threadIdx.x >> 6, lane = threadIdx.x & 63;
  __syncthreads();
  if (lane == 0) red[wid] = x;
  __syncthreads();
  float s = 0.f;
  #pragma unroll
  for (int j = 0; j < 16; ++j) s += red[j];
  return s;
}
__device__ __forceinline__ float blk_red_max16(float x, float* red){
  #pragma unroll
  for (int o = 32; o > 0; o >>= 1) x = fmaxf(x, __shfl_xor(x, o));
  int wid = threadIdx.x >> 6, lane = threadIdx.x & 63;
  __syncthreads();
  if (lane == 0) red[wid] = x;
  __syncthreads();
  float s = red[0];
  #pragma unroll
  for (int j = 1; j < 16; ++j) s = fmaxf(s, red[j]);
  return s;
}

__global__ __launch_bounds__(1024) void k_final(const float* __restrict__ s, const float* __restrict__ vv,
    const float* __restrict__ cbp, const float* __restrict__ gamma, const float* __restrict__ beta,
    float* __restrict__ out){
  __shared__ float t[NG];
  __shared__ float red[16];
  int b = blockIdx.x, tid = threadIdx.x;
  float cb = cbp[0];
  const float inv = 1.f / (float)HD;
  float lsum = 0.f, lsq = 0.f;
  for (int j = tid; j < NG; j += 1024){
    float g = (s[b*NPG + j] + vv[b*NPG + j] + cb) * inv;
    t[j] = g; lsum += g; lsq += g * g;
  }
  float S1 = blk_red_add16(lsum, red);
  float S2 = blk_red_add16(lsq, red);
  float mu = S1 / (float)NG;
  float var = S2 / (float)NG - mu * mu;
  float rstd = rsqrtf(var + 1e-5f);
  float lmax = -3.4e38f;
  for (int j = tid; j < NG; j += 1024){
    float tj = (t[j] - mu) * rstd * gamma[j] + beta[j];
    t[j] = tj; lmax = fmaxf(lmax, tj);
  }
  float M = blk_red_max16(lmax, red);
  float lexp = 0.f;
  for (int j = tid; j < NG; j += 1024) lexp += expf(t[j] - M);
  float S = blk_red_add16(lexp, red);
  float lse = M + logf(S);
  for (int j = tid; j < NG; j += 1024) out[b*NG + j] = t[j] - lse;
}

extern "C" void kernel_launch(void* const* d_in, const int* in_sizes, int n_in,
                              void* d_out, int out_size, void* d_ws, size_t ws_size,
                              hipStream_t stream){
  const float* x      = (const float*)d_in[0];
  const int*   ei     = (const int*)d_in[1];
  const float* ew     = (const float*)d_in[3];
  const float* Wrel1  = (const float*)d_in[4];
  const float* brel1  = (const float*)d_in[5];
  const float* Wroot1 = (const float*)d_in[6];
  const float* Wrel2  = (const float*)d_in[7];
  const float* brel2  = (const float*)d_in[8];
  const float* Wroot2 = (const float*)d_in[9];
  const float* gamma  = (const float*)d_in[10];
  const float* beta   = (const float*)d_in[11];
  const int*   src    = ei;
  const int*   dst    = ei + NE;

  char* ws = (char*)d_ws;
  size_t off_b = 0;
  auto alloc = [&](size_t bytes) -> char* {
    char* p = ws + off_b;
    off_b += (bytes + 511) & ~(size_t)511;
    return p;
  };
  unsigned short* xb    = (unsigned short*)alloc((size_t)TN * HD * 2);
  unsigned short* zb    = (unsigned short*)alloc((size_t)TN * HD * 2);
  unsigned short* W1b   = (unsigned short*)alloc(HD * HD * 2);
  unsigned short* W2b   = (unsigned short*)alloc(HD * HD * 2);
  float*          crel  = (float*)alloc(HD * 4);
  float*          croot = (float*)alloc(HD * 4);
  float*          cbp   = (float*)alloc(4);
  float*          u     = (float*)alloc(TN * 4);
  float*          v     = (float*)alloc(TN * 4);
  float*          sacc  = (float*)alloc(TN * 4);
  int*            startp= (int*)alloc(TN * 4);
  int*            cntp  = (int*)alloc(TN * 4);
  int*            gcur  = (int*)alloc(NBUCK * 4);
  int2*           rec   = (int2*)alloc((size_t)NBUCK * BCAP * 8);

  hipMemsetAsync(gcur, 0, NBUCK * 4, stream);

  k_prepbin<<<NCHUNK + 1 + PX_BLK + PW_BLK, 512, 0, stream>>>(
      Wrel2, Wroot2, brel2, crel, croot, cbp,
      src, dst, ew, gcur, rec,
      x, xb, Wrel1, Wroot1, W1b, W2b);
  k_nsort <<<NBUCK, 512, 0, stream>>>(gcur, rec, startp, cntp);
  k_gather<<<TN/4, 256, 0, stream>>>(startp, cntp, rec, xb, zb);
  k_node  <<<TN/128, 256, 0, stream>>>(zb, xb, W1b, W2b, brel1, crel, croot, u, v);
  k_pool2 <<<(TN+15)/16, 256, 0, stream>>>(startp, cntp, rec, u, sacc);
  k_final <<<NB, 1024, 0, stream>>>(sacc, v, cbp, gamma, beta, (float*)d_out);
}